// Round 15
// baseline (72.325 us; speedup 1.0000x reference)
//
#include <hip/hip_runtime.h>
#include <math.h>

// Problem constants
#define BB 32
#define TT 4096
#define DD 512
#define SS 256
#define WPB 96            // waves per batch (96*32 batches = 3072 waves total)
#define NBLK 768          // 768 blocks * 4 waves = 3072; 3 blocks/CU, all resident
static constexpr float INV_SCALE = 10.0f;   // 1/0.1

typedef float f32x4 __attribute__((ext_vector_type(4)));   // for NT stores

// ---------------------------------------------------------------------------
// Kernel 1: q = silu(t_star*W1+b1) @ W2 + b2.  Also zeroes per-batch counters.
// ---------------------------------------------------------------------------
__global__ __launch_bounds__(512) void k_q(
    const float* __restrict__ t_star, const float* __restrict__ W1,
    const float* __restrict__ b1, const float* __restrict__ W2,
    const float* __restrict__ b2, float* __restrict__ q,
    int* __restrict__ cnt) {
  const int b   = blockIdx.x >> 3;
  const int jg  = blockIdx.x & 7;
  const int tid = threadIdx.x;
  const int di  = tid & 63;
  const int kg  = tid >> 6;
  if (tid == 0 && blockIdx.x < BB) cnt[blockIdx.x] = 0;   // reset for k_merge_out
  __shared__ float h[DD];
  __shared__ float red[8][64];
  {
    float x = t_star[b] * W1[tid] + b1[tid];
    h[tid] = x / (1.0f + __expf(-x));     // silu
  }
  __syncthreads();
  const float* w = W2 + jg * 64 + di;
  float acc = 0.0f;
#pragma unroll 8
  for (int kk = 0; kk < 64; ++kk) {
    const int k = kg * 64 + kk;
    acc += h[k] * w[(size_t)k * DD];
  }
  red[kg][di] = acc;
  __syncthreads();
  if (tid < 64) {
    float s = 0.0f;
#pragma unroll
    for (int g = 0; g < 8; ++g) s += red[g][tid];
    q[b * DD + jg * 64 + tid] = s + b2[jg * 64 + tid];
  }
}

// ---------------------------------------------------------------------------
// Kernel 2: LDS-staged flash pooling — persistent balanced grid (R14, best).
// 768 blocks (3/CU, all resident) x 4 waves; batch b owns waves [96b,96b+96).
// 3-slot ring, depth-2 prefetch, NT staging, vmcnt(8) steady.
// ---------------------------------------------------------------------------
#define GLDS(gp, lp)                                                        \
  __builtin_amdgcn_global_load_lds(                                         \
      (const __attribute__((address_space(1))) void*)(gp),                  \
      (__attribute__((address_space(3))) void*)(lp), 16, 0, 2 /*NT*/)

__global__ __launch_bounds__(256) void k_fused(
    const float* __restrict__ ctx, const float* __restrict__ q,
    const float* __restrict__ t_star, const float* __restrict__ t_ctx,
    float* __restrict__ part_pool,    // [B*WPB*DD]
    float* __restrict__ part_ms) {    // [B*WPB*2]  (m, l)
  __shared__ __align__(16) float lds[4][3][2 * DD];   // 48 KB
  const int wid  = threadIdx.x >> 6;
  const int lane = threadIdx.x & 63;
  const int W    = blockIdx.x * 4 + wid;   // global wave id, 0..3071
  const int b    = W / WPB;                // batch
  const int v    = W % WPB;                // wave-in-batch, 0..95
  const int NG   = (v < 32) ? 22 : 21;     // groups for this wave

  const float4* qp = (const float4*)(q + b * DD);
  const float4 q0 = qp[lane];
  const float4 q1 = qp[64 + lane];
  const float ts = t_star[b];

  // lane g (g < NG) holds the time-bias pair for its step's rows
  const int lg = lane & 31;
  int gidx = lg * WPB + v;
  if (gidx >= TT / 2) gidx = v;            // clamp unused lanes in-bounds
  const float2 tc = *(const float2*)(t_ctx + b * TT + 2 * gidx);
  const float tbx = -fabsf(ts - tc.x) * INV_SCALE;
  const float tby = -fabsf(ts - tc.y) * INV_SCALE;

  float m = -INFINITY, l = 0.0f;
  float4 p0 = {0, 0, 0, 0}, p1 = {0, 0, 0, 0};

  const float* cbatch = ctx + (size_t)b * TT * DD;

  // prologue: stage groups 0,1 into slots 0,1 (every wave has NG >= 21)
#pragma unroll
  for (int g = 0; g < 2; ++g) {
    const float* gb = cbatch + (size_t)(g * WPB + v) * 2 * DD;
    float* sb = &lds[wid][g][0];
#pragma unroll
    for (int piece = 0; piece < 4; ++piece)
      GLDS(gb + piece * 256 + lane * 4, sb + piece * 256);
  }

  int rs = 0, wslot = 2;                   // read slot, write slot (mod-3 ring)
  for (int g = 0; g < NG; ++g) {
    if (g + 2 < NG) {
      const float* gb = cbatch + (size_t)((g + 2) * WPB + v) * 2 * DD;
      float* sb = &lds[wid][wslot][0];
#pragma unroll
      for (int piece = 0; piece < 4; ++piece)
        GLDS(gb + piece * 256 + lane * 4, sb + piece * 256);
      asm volatile("s_waitcnt vmcnt(8)" ::: "memory");   // group g resident
    } else if (g + 2 == NG) {
      asm volatile("s_waitcnt vmcnt(4)" ::: "memory");
    } else {
      asm volatile("s_waitcnt vmcnt(0)" ::: "memory");
    }

    const float4* sf = (const float4*)&lds[wid][rs][0];
    const float4 x0 = sf[lane];        // row0 dims [lane*4 .. +3]
    const float4 x1 = sf[64 + lane];   // row0 dims [256+lane*4 ..]
    const float4 y0 = sf[128 + lane];  // row1
    const float4 y1 = sf[192 + lane];

    float s0 = x0.x * q0.x + x0.y * q0.y + x0.z * q0.z + x0.w * q0.w +
               x1.x * q1.x + x1.y * q1.y + x1.z * q1.z + x1.w * q1.w;
    float s1 = y0.x * q0.x + y0.y * q0.y + y0.z * q0.z + y0.w * q0.w +
               y1.x * q1.x + y1.y * q1.y + y1.z * q1.z + y1.w * q1.w;
#pragma unroll
    for (int off = 32; off > 0; off >>= 1) {
      s0 += __shfl_xor(s0, off);
      s1 += __shfl_xor(s1, off);
    }
    s0 += __shfl(tbx, g);
    s1 += __shfl(tby, g);

    const float gm = fmaxf(s0, s1);
    const float nm = fmaxf(m, gm);
    const float sc = __expf(m - nm);   // g==0: exp(-inf)=0, p=l=0 anyway
    m = nm;
    const float e0 = __expf(s0 - m);
    const float e1 = __expf(s1 - m);
    l = l * sc + e0 + e1;
    p0.x = p0.x * sc + e0 * x0.x + e1 * y0.x;
    p0.y = p0.y * sc + e0 * x0.y + e1 * y0.y;
    p0.z = p0.z * sc + e0 * x0.z + e1 * y0.z;
    p0.w = p0.w * sc + e0 * x0.w + e1 * y0.w;
    p1.x = p1.x * sc + e0 * x1.x + e1 * y1.x;
    p1.y = p1.y * sc + e0 * x1.y + e1 * y1.y;
    p1.z = p1.z * sc + e0 * x1.z + e1 * y1.z;
    p1.w = p1.w * sc + e0 * x1.w + e1 * y1.w;

    rs = (rs == 2) ? 0 : rs + 1;
    wslot = (wslot == 2) ? 0 : wslot + 1;
  }

  // NT store of partials (single-use stream, consumed by k_merge_out)
  f32x4* pp = (f32x4*)(part_pool + (size_t)W * DD);
  f32x4 v0 = {p0.x, p0.y, p0.z, p0.w};
  f32x4 v1 = {p1.x, p1.y, p1.z, p1.w};
  __builtin_nontemporal_store(v0, pp + lane);
  __builtin_nontemporal_store(v1, pp + 64 + lane);
  if (lane == 0) {
    part_ms[W * 2 + 0] = m;
    part_ms[W * 2 + 1] = l;
  }
}

// ---------------------------------------------------------------------------
// Kernel 3 (merged epilogue): per (b, dg of 8): merge the 96 partials into a
// 64-dim pool slice, publish via __threadfence+atomicAdd, spin until all 8
// slices of the batch are done (all 256 blocks co-resident: 4/CU capacity),
// then compute this block's 64-col slab of out = pool @ Wout + bout.
// Deterministic: each pool dim / out col is produced by exactly one block.
// ---------------------------------------------------------------------------
__global__ __launch_bounds__(512) void k_merge_out(
    const float* __restrict__ part_pool, const float* __restrict__ part_ms,
    const float* __restrict__ Wout, const float* __restrict__ bout,
    float* __restrict__ pool, int* __restrict__ cnt, float* __restrict__ out) {
  const int b   = blockIdx.x >> 3;
  const int dg  = blockIdx.x & 7;
  const int tid = threadIdx.x;
  const int lane = tid & 63;
  const int base = b * WPB;
  __shared__ float scl[WPB];
  __shared__ float red[8][64];
  __shared__ float pool_s[DD];

  // wave-parallel global (M, Z) over 96 partials (each wave redundantly)
  const float mA = part_ms[(base + lane) * 2 + 0];
  const float lA = part_ms[(base + lane) * 2 + 1];
  float mB = -INFINITY, lB = 0.0f;
  if (lane < WPB - 64) {
    mB = part_ms[(base + 64 + lane) * 2 + 0];
    lB = part_ms[(base + 64 + lane) * 2 + 1];
  }
  float M = fmaxf(mA, mB);
#pragma unroll
  for (int off = 32; off > 0; off >>= 1) M = fmaxf(M, __shfl_xor(M, off));
  float Z = __expf(mA - M) * lA + ((lane < WPB - 64) ? __expf(mB - M) * lB : 0.0f);
#pragma unroll
  for (int off = 32; off > 0; off >>= 1) Z += __shfl_xor(Z, off);
  const float invZ = 1.0f / Z;
  if (tid < WPB) scl[tid] = __expf(part_ms[(base + tid) * 2] - M);
  __syncthreads();

  // merge this block's 64-dim slice over 96 chunks (8 groups x 12)
  const int dl = tid & 63;
  const int cg = tid >> 6;
  const int d  = dg * 64 + dl;
  float acc = 0.0f;
#pragma unroll
  for (int i = 0; i < 12; ++i) {
    const int c = cg * 12 + i;
    acc += scl[c] *
           __builtin_nontemporal_load(&part_pool[((size_t)base + c) * DD + d]);
  }
  red[cg][dl] = acc;
  __syncthreads();
  if (tid < 64) {
    float s = 0.0f;
#pragma unroll
    for (int g = 0; g < 8; ++g) s += red[g][tid];
    pool[b * DD + dg * 64 + tid] = s * invZ;
  }
  __syncthreads();                         // slice stores complete (vmcnt drained)

  // publish slice, wait for all 8 slices of this batch
  if (tid == 0) {
    __threadfence();                       // release: flush slice to device scope
    atomicAdd(&cnt[b], 1);
    while (atomicAdd(&cnt[b], 0) < 8) __builtin_amdgcn_s_sleep(8);
    __threadfence();                       // acquire
  }
  __syncthreads();

  // Wout phase: this block computes cols [dg*64, dg*64+64)
  pool_s[tid] = pool[b * DD + tid];        // full 512-dim pool (fresh via fence)
  if (tid < DD - 512) {}                   // (DD==512; single load per thread)
  __syncthreads();

  const int j  = dg * 64 + (tid & 63);
  const int kg = tid >> 6;
  float a2 = 0.0f;
#pragma unroll 8
  for (int kk = 0; kk < 64; ++kk) {
    const int k = kg * 64 + kk;
    a2 += pool_s[k] * Wout[(size_t)k * DD + j];
  }
  red[kg][tid & 63] = a2;
  __syncthreads();
  if (tid < 64) {
    const int jj = dg * 64 + tid;
    float o = bout[jj];
#pragma unroll
    for (int g = 0; g < 8; ++g) o += red[g][tid];
    if (jj < SS) out[b * SS + jj] = o;                       // mu
    else         out[BB * SS + b * SS + (jj - SS)] = o;      // log_sigma
  }
}

// ---------------------------------------------------------------------------
extern "C" void kernel_launch(void* const* d_in, const int* in_sizes, int n_in,
                              void* d_out, int out_size, void* d_ws, size_t ws_size,
                              hipStream_t stream) {
  const float* ctx    = (const float*)d_in[0];   // (B,T,D)
  const float* t_star = (const float*)d_in[1];   // (B,)
  const float* t_ctx  = (const float*)d_in[2];   // (B,T,1)
  const float* W1     = (const float*)d_in[3];   // (1,D)
  const float* b1     = (const float*)d_in[4];   // (D,)
  const float* W2     = (const float*)d_in[5];   // (D,D)
  const float* b2     = (const float*)d_in[6];   // (D,)
  const float* Wout   = (const float*)d_in[7];   // (D,2S)
  const float* bout   = (const float*)d_in[8];   // (2S,)
  float* out = (float*)d_out;

  float* ws = (float*)d_ws;
  float* q         = ws;                                   // B*D
  float* part_pool = q + (size_t)BB * DD;                  // B*WPB*D (6.3 MB)
  float* part_ms   = part_pool + (size_t)BB * WPB * DD;    // B*WPB*2
  float* pool      = part_ms + (size_t)BB * WPB * 2;       // B*D
  int*   cnt       = (int*)(pool + (size_t)BB * DD);       // B counters

  k_q<<<BB * 8, 512, 0, stream>>>(t_star, W1, b1, W2, b2, q, cnt);
  k_fused<<<NBLK, 256, 0, stream>>>(ctx, q, t_star, t_ctx, part_pool, part_ms);
  k_merge_out<<<BB * 8, 512, 0, stream>>>(part_pool, part_ms, Wout, bout,
                                          pool, cnt, out);
}

// Round 16
// 66.875 us; speedup vs baseline: 1.0815x; 1.0815x over previous
//
#include <hip/hip_runtime.h>
#include <math.h>

// Problem constants
#define BB 32
#define TT 4096
#define DD 512
#define SS 256
#define WPB 96            // waves per batch (96*32 batches = 3072 waves total)
#define NBLK 768          // 768 blocks * 4 waves = 3072; 3 blocks/CU, all resident
static constexpr float INV_SCALE = 10.0f;   // 1/0.1

// ---------------------------------------------------------------------------
// Kernel 1: q = silu(t_star*W1+b1) @ W2 + b2.
// ---------------------------------------------------------------------------
__global__ __launch_bounds__(512) void k_q(
    const float* __restrict__ t_star, const float* __restrict__ W1,
    const float* __restrict__ b1, const float* __restrict__ W2,
    const float* __restrict__ b2, float* __restrict__ q) {
  const int b   = blockIdx.x >> 3;
  const int jg  = blockIdx.x & 7;
  const int tid = threadIdx.x;
  const int di  = tid & 63;
  const int kg  = tid >> 6;
  __shared__ float h[DD];
  __shared__ float red[8][64];
  {
    float x = t_star[b] * W1[tid] + b1[tid];
    h[tid] = x / (1.0f + __expf(-x));     // silu
  }
  __syncthreads();
  const float* w = W2 + jg * 64 + di;
  float acc = 0.0f;
#pragma unroll 8
  for (int kk = 0; kk < 64; ++kk) {
    const int k = kg * 64 + kk;
    acc += h[k] * w[(size_t)k * DD];
  }
  red[kg][di] = acc;
  __syncthreads();
  if (tid < 64) {
    float s = 0.0f;
#pragma unroll
    for (int g = 0; g < 8; ++g) s += red[g][tid];
    q[b * DD + jg * 64 + tid] = s + b2[jg * 64 + tid];
  }
}

// ---------------------------------------------------------------------------
// Kernel 2: LDS-staged flash pooling — persistent balanced grid (R14, best).
// 768 blocks (3/CU at 48 KB, all resident) x 4 waves = 3072 waves.
// Batch b owns waves [96b, 96b+96); wave v<32: 22 groups, else 21.
// 3-slot ring, depth-2 prefetch, NT staging loads, vmcnt(8) steady.
// Partial stores are CACHED (read 8x by k_epi).
// ---------------------------------------------------------------------------
#define GLDS(gp, lp)                                                        \
  __builtin_amdgcn_global_load_lds(                                         \
      (const __attribute__((address_space(1))) void*)(gp),                  \
      (__attribute__((address_space(3))) void*)(lp), 16, 0, 2 /*NT*/)

__global__ __launch_bounds__(256) void k_fused(
    const float* __restrict__ ctx, const float* __restrict__ q,
    const float* __restrict__ t_star, const float* __restrict__ t_ctx,
    float* __restrict__ part_pool,    // [B*WPB*DD]
    float* __restrict__ part_ms) {    // [B*WPB*2]  (m, l)
  __shared__ __align__(16) float lds[4][3][2 * DD];   // 48 KB
  const int wid  = threadIdx.x >> 6;
  const int lane = threadIdx.x & 63;
  const int W    = blockIdx.x * 4 + wid;   // global wave id, 0..3071
  const int b    = W / WPB;                // batch
  const int v    = W % WPB;                // wave-in-batch, 0..95
  const int NG   = (v < 32) ? 22 : 21;     // groups for this wave

  const float4* qp = (const float4*)(q + b * DD);
  const float4 q0 = qp[lane];
  const float4 q1 = qp[64 + lane];
  const float ts = t_star[b];

  // lane g (g < NG) holds the time-bias pair for its step's rows
  const int lg = lane & 31;
  int gidx = lg * WPB + v;
  if (gidx >= TT / 2) gidx = v;            // clamp unused lanes in-bounds
  const float2 tc = *(const float2*)(t_ctx + b * TT + 2 * gidx);
  const float tbx = -fabsf(ts - tc.x) * INV_SCALE;
  const float tby = -fabsf(ts - tc.y) * INV_SCALE;

  float m = -INFINITY, l = 0.0f;
  float4 p0 = {0, 0, 0, 0}, p1 = {0, 0, 0, 0};

  const float* cbatch = ctx + (size_t)b * TT * DD;

  // prologue: stage groups 0,1 into slots 0,1 (every wave has NG >= 21)
#pragma unroll
  for (int g = 0; g < 2; ++g) {
    const float* gb = cbatch + (size_t)(g * WPB + v) * 2 * DD;
    float* sb = &lds[wid][g][0];
#pragma unroll
    for (int piece = 0; piece < 4; ++piece)
      GLDS(gb + piece * 256 + lane * 4, sb + piece * 256);
  }

  int rs = 0, wslot = 2;                   // read slot, write slot (mod-3 ring)
  for (int g = 0; g < NG; ++g) {
    if (g + 2 < NG) {
      const float* gb = cbatch + (size_t)((g + 2) * WPB + v) * 2 * DD;
      float* sb = &lds[wid][wslot][0];
#pragma unroll
      for (int piece = 0; piece < 4; ++piece)
        GLDS(gb + piece * 256 + lane * 4, sb + piece * 256);
      asm volatile("s_waitcnt vmcnt(8)" ::: "memory");   // group g resident
    } else if (g + 2 == NG) {
      asm volatile("s_waitcnt vmcnt(4)" ::: "memory");
    } else {
      asm volatile("s_waitcnt vmcnt(0)" ::: "memory");
    }

    const float4* sf = (const float4*)&lds[wid][rs][0];
    const float4 x0 = sf[lane];        // row0 dims [lane*4 .. +3]
    const float4 x1 = sf[64 + lane];   // row0 dims [256+lane*4 ..]
    const float4 y0 = sf[128 + lane];  // row1
    const float4 y1 = sf[192 + lane];

    float s0 = x0.x * q0.x + x0.y * q0.y + x0.z * q0.z + x0.w * q0.w +
               x1.x * q1.x + x1.y * q1.y + x1.z * q1.z + x1.w * q1.w;
    float s1 = y0.x * q0.x + y0.y * q0.y + y0.z * q0.z + y0.w * q0.w +
               y1.x * q1.x + y1.y * q1.y + y1.z * q1.z + y1.w * q1.w;
#pragma unroll
    for (int off = 32; off > 0; off >>= 1) {
      s0 += __shfl_xor(s0, off);
      s1 += __shfl_xor(s1, off);
    }
    s0 += __shfl(tbx, g);
    s1 += __shfl(tby, g);

    const float gm = fmaxf(s0, s1);
    const float nm = fmaxf(m, gm);
    const float sc = __expf(m - nm);   // g==0: exp(-inf)=0, p=l=0 anyway
    m = nm;
    const float e0 = __expf(s0 - m);
    const float e1 = __expf(s1 - m);
    l = l * sc + e0 + e1;
    p0.x = p0.x * sc + e0 * x0.x + e1 * y0.x;
    p0.y = p0.y * sc + e0 * x0.y + e1 * y0.y;
    p0.z = p0.z * sc + e0 * x0.z + e1 * y0.z;
    p0.w = p0.w * sc + e0 * x0.w + e1 * y0.w;
    p1.x = p1.x * sc + e0 * x1.x + e1 * y1.x;
    p1.y = p1.y * sc + e0 * x1.y + e1 * y1.y;
    p1.z = p1.z * sc + e0 * x1.z + e1 * y1.z;
    p1.w = p1.w * sc + e0 * x1.w + e1 * y1.w;

    rs = (rs == 2) ? 0 : rs + 1;
    wslot = (wslot == 2) ? 0 : wslot + 1;
  }

  // cached store of partials (k_epi reads them 8x)
  float4* pp = (float4*)(part_pool + (size_t)W * DD);
  pp[lane] = p0;
  pp[64 + lane] = p1;
  if (lane == 0) {
    part_ms[W * 2 + 0] = m;
    part_ms[W * 2 + 1] = l;
  }
}

// ---------------------------------------------------------------------------
// Kernel 3 (fused epilogue, no inter-block sync): grid = B*8 (b, jg);
// block 512. Each block redundantly merges the FULL 512-dim pool for its
// batch (96 partials x 512 dims, ~196 KB, L2/L3-resident) then computes its
// own 64-col slab of out = pool @ Wout + bout. No spin, no pool round-trip.
// ---------------------------------------------------------------------------
__global__ __launch_bounds__(512) void k_epi(
    const float* __restrict__ part_pool, const float* __restrict__ part_ms,
    const float* __restrict__ Wout, const float* __restrict__ bout,
    float* __restrict__ out) {
  const int b   = blockIdx.x >> 3;
  const int jg  = blockIdx.x & 7;
  const int tid = threadIdx.x;
  const int lane = tid & 63;
  const int base = b * WPB;
  __shared__ float scl[WPB];
  __shared__ float pool_s[DD];
  __shared__ float red[8][64];

  // wave-parallel global (M, Z) over 96 partials (each wave redundantly)
  const float mA = part_ms[(base + lane) * 2 + 0];
  const float lA = part_ms[(base + lane) * 2 + 1];
  float mB = -INFINITY, lB = 0.0f;
  if (lane < WPB - 64) {
    mB = part_ms[(base + 64 + lane) * 2 + 0];
    lB = part_ms[(base + 64 + lane) * 2 + 1];
  }
  float M = fmaxf(mA, mB);
#pragma unroll
  for (int off = 32; off > 0; off >>= 1) M = fmaxf(M, __shfl_xor(M, off));
  float Z = __expf(mA - M) * lA + ((lane < WPB - 64) ? __expf(mB - M) * lB : 0.0f);
#pragma unroll
  for (int off = 32; off > 0; off >>= 1) Z += __shfl_xor(Z, off);
  const float invZ = 1.0f / Z;
  if (tid < WPB) scl[tid] = __expf(part_ms[(base + tid) * 2] - M);
  __syncthreads();

  // full-pool merge: thread tid owns dim tid (96 cached MACs)
  {
    float acc = 0.0f;
#pragma unroll 8
    for (int c = 0; c < WPB; ++c)
      acc += scl[c] * part_pool[((size_t)base + c) * DD + tid];
    pool_s[tid] = acc * invZ;
  }
  __syncthreads();

  // Wout slab: cols [jg*64, jg*64+64), 8 k-groups x 64 cols
  const int j  = jg * 64 + (tid & 63);
  const int kg = tid >> 6;
  float a2 = 0.0f;
#pragma unroll 8
  for (int kk = 0; kk < 64; ++kk) {
    const int k = kg * 64 + kk;
    a2 += pool_s[k] * Wout[(size_t)k * DD + j];
  }
  red[kg][tid & 63] = a2;
  __syncthreads();
  if (tid < 64) {
    const int jj = jg * 64 + tid;
    float o = bout[jj];
#pragma unroll
    for (int g = 0; g < 8; ++g) o += red[g][tid];
    if (jj < SS) out[b * SS + jj] = o;                       // mu
    else         out[BB * SS + b * SS + (jj - SS)] = o;      // log_sigma
  }
}

// ---------------------------------------------------------------------------
extern "C" void kernel_launch(void* const* d_in, const int* in_sizes, int n_in,
                              void* d_out, int out_size, void* d_ws, size_t ws_size,
                              hipStream_t stream) {
  const float* ctx    = (const float*)d_in[0];   // (B,T,D)
  const float* t_star = (const float*)d_in[1];   // (B,)
  const float* t_ctx  = (const float*)d_in[2];   // (B,T,1)
  const float* W1     = (const float*)d_in[3];   // (1,D)
  const float* b1     = (const float*)d_in[4];   // (D,)
  const float* W2     = (const float*)d_in[5];   // (D,D)
  const float* b2     = (const float*)d_in[6];   // (D,)
  const float* Wout   = (const float*)d_in[7];   // (D,2S)
  const float* bout   = (const float*)d_in[8];   // (2S,)
  float* out = (float*)d_out;

  float* ws = (float*)d_ws;
  float* q         = ws;                                   // B*D
  float* part_pool = q + (size_t)BB * DD;                  // B*WPB*D (6.3 MB)
  float* part_ms   = part_pool + (size_t)BB * WPB * DD;    // B*WPB*2

  k_q<<<BB * 8, 512, 0, stream>>>(t_star, W1, b1, W2, b2, q);
  k_fused<<<NBLK, 256, 0, stream>>>(ctx, q, t_star, t_ctx, part_pool, part_ms);
  k_epi<<<BB * 8, 512, 0, stream>>>(part_pool, part_ms, Wout, bout, out);
}

// Round 17
// 61.695 us; speedup vs baseline: 1.1723x; 1.0840x over previous
//
#include <hip/hip_runtime.h>
#include <math.h>

// Problem constants
#define BB 32
#define TT 4096
#define DD 512
#define SS 256
#define WPB 96            // waves per batch (96*32 batches = 3072 waves total)
#define NBLK 768          // 768 blocks * 4 waves = 3072; 3 blocks/CU, all resident
static constexpr float INV_SCALE = 10.0f;   // 1/0.1

typedef float f32x4 __attribute__((ext_vector_type(4)));   // for NT stores

// ---------------------------------------------------------------------------
// Kernel 1: q = silu(t_star*W1+b1) @ W2 + b2.
// ---------------------------------------------------------------------------
__global__ __launch_bounds__(512) void k_q(
    const float* __restrict__ t_star, const float* __restrict__ W1,
    const float* __restrict__ b1, const float* __restrict__ W2,
    const float* __restrict__ b2, float* __restrict__ q) {
  const int b   = blockIdx.x >> 3;
  const int jg  = blockIdx.x & 7;
  const int tid = threadIdx.x;
  const int di  = tid & 63;
  const int kg  = tid >> 6;
  __shared__ float h[DD];
  __shared__ float red[8][64];
  {
    float x = t_star[b] * W1[tid] + b1[tid];
    h[tid] = x / (1.0f + __expf(-x));     // silu
  }
  __syncthreads();
  const float* w = W2 + jg * 64 + di;
  float acc = 0.0f;
#pragma unroll 8
  for (int kk = 0; kk < 64; ++kk) {
    const int k = kg * 64 + kk;
    acc += h[k] * w[(size_t)k * DD];
  }
  red[kg][di] = acc;
  __syncthreads();
  if (tid < 64) {
    float s = 0.0f;
#pragma unroll
    for (int g = 0; g < 8; ++g) s += red[g][tid];
    q[b * DD + jg * 64 + tid] = s + b2[jg * 64 + tid];
  }
}

// ---------------------------------------------------------------------------
// Kernel 2: LDS-staged flash pooling — persistent balanced grid (best, R14).
// 768 blocks (= 3/CU at 48 KB, ALL resident) x 4 waves = 3072 waves.
// Batch b owns waves [96b, 96b+96); wave v<32 gets 22 two-row groups,
// v>=32 gets 21 (2048 groups/batch, max imbalance 3%). Group g of wave v
// covers rows {2*(g*96+v), +1} (strided coherent front).
// 3-slot ring, depth-2 prefetch, NT staging, vmcnt(8) steady.
// No __syncthreads, no cross-wave LDS sharing.
// ---------------------------------------------------------------------------
#define GLDS(gp, lp)                                                        \
  __builtin_amdgcn_global_load_lds(                                         \
      (const __attribute__((address_space(1))) void*)(gp),                  \
      (__attribute__((address_space(3))) void*)(lp), 16, 0, 2 /*NT*/)

__global__ __launch_bounds__(256) void k_fused(
    const float* __restrict__ ctx, const float* __restrict__ q,
    const float* __restrict__ t_star, const float* __restrict__ t_ctx,
    float* __restrict__ part_pool,    // [B*WPB*DD]
    float* __restrict__ part_ms) {    // [B*WPB*2]  (m, l)
  __shared__ __align__(16) float lds[4][3][2 * DD];   // 48 KB
  const int wid  = threadIdx.x >> 6;
  const int lane = threadIdx.x & 63;
  const int W    = blockIdx.x * 4 + wid;   // global wave id, 0..3071
  const int b    = W / WPB;                // batch
  const int v    = W % WPB;                // wave-in-batch, 0..95
  const int NG   = (v < 32) ? 22 : 21;     // groups for this wave

  const float4* qp = (const float4*)(q + b * DD);
  const float4 q0 = qp[lane];
  const float4 q1 = qp[64 + lane];
  const float ts = t_star[b];

  // lane g (g < NG) holds the time-bias pair for its step's rows
  const int lg = lane & 31;
  int gidx = lg * WPB + v;
  if (gidx >= TT / 2) gidx = v;            // clamp unused lanes in-bounds
  const float2 tc = *(const float2*)(t_ctx + b * TT + 2 * gidx);
  const float tbx = -fabsf(ts - tc.x) * INV_SCALE;
  const float tby = -fabsf(ts - tc.y) * INV_SCALE;

  float m = -INFINITY, l = 0.0f;
  float4 p0 = {0, 0, 0, 0}, p1 = {0, 0, 0, 0};

  const float* cbatch = ctx + (size_t)b * TT * DD;

  // prologue: stage groups 0,1 into slots 0,1 (every wave has NG >= 21)
#pragma unroll
  for (int g = 0; g < 2; ++g) {
    const float* gb = cbatch + (size_t)(g * WPB + v) * 2 * DD;
    float* sb = &lds[wid][g][0];
#pragma unroll
    for (int piece = 0; piece < 4; ++piece)
      GLDS(gb + piece * 256 + lane * 4, sb + piece * 256);
  }

  int rs = 0, wslot = 2;                   // read slot, write slot (mod-3 ring)
  for (int g = 0; g < NG; ++g) {
    if (g + 2 < NG) {
      const float* gb = cbatch + (size_t)((g + 2) * WPB + v) * 2 * DD;
      float* sb = &lds[wid][wslot][0];
#pragma unroll
      for (int piece = 0; piece < 4; ++piece)
        GLDS(gb + piece * 256 + lane * 4, sb + piece * 256);
      asm volatile("s_waitcnt vmcnt(8)" ::: "memory");   // group g resident
    } else if (g + 2 == NG) {
      asm volatile("s_waitcnt vmcnt(4)" ::: "memory");
    } else {
      asm volatile("s_waitcnt vmcnt(0)" ::: "memory");
    }

    const float4* sf = (const float4*)&lds[wid][rs][0];
    const float4 x0 = sf[lane];        // row0 dims [lane*4 .. +3]
    const float4 x1 = sf[64 + lane];   // row0 dims [256+lane*4 ..]
    const float4 y0 = sf[128 + lane];  // row1
    const float4 y1 = sf[192 + lane];

    float s0 = x0.x * q0.x + x0.y * q0.y + x0.z * q0.z + x0.w * q0.w +
               x1.x * q1.x + x1.y * q1.y + x1.z * q1.z + x1.w * q1.w;
    float s1 = y0.x * q0.x + y0.y * q0.y + y0.z * q0.z + y0.w * q0.w +
               y1.x * q1.x + y1.y * q1.y + y1.z * q1.z + y1.w * q1.w;
#pragma unroll
    for (int off = 32; off > 0; off >>= 1) {
      s0 += __shfl_xor(s0, off);
      s1 += __shfl_xor(s1, off);
    }
    s0 += __shfl(tbx, g);
    s1 += __shfl(tby, g);

    const float gm = fmaxf(s0, s1);
    const float nm = fmaxf(m, gm);
    const float sc = __expf(m - nm);   // g==0: exp(-inf)=0, p=l=0 anyway
    m = nm;
    const float e0 = __expf(s0 - m);
    const float e1 = __expf(s1 - m);
    l = l * sc + e0 + e1;
    p0.x = p0.x * sc + e0 * x0.x + e1 * y0.x;
    p0.y = p0.y * sc + e0 * x0.y + e1 * y0.y;
    p0.z = p0.z * sc + e0 * x0.z + e1 * y0.z;
    p0.w = p0.w * sc + e0 * x0.w + e1 * y0.w;
    p1.x = p1.x * sc + e0 * x1.x + e1 * y1.x;
    p1.y = p1.y * sc + e0 * x1.y + e1 * y1.y;
    p1.z = p1.z * sc + e0 * x1.z + e1 * y1.z;
    p1.w = p1.w * sc + e0 * x1.w + e1 * y1.w;

    rs = (rs == 2) ? 0 : rs + 1;
    wslot = (wslot == 2) ? 0 : wslot + 1;
  }

  // NT store of partials (single-use stream, consumed once by k_merge)
  f32x4* pp = (f32x4*)(part_pool + (size_t)W * DD);
  f32x4 v0 = {p0.x, p0.y, p0.z, p0.w};
  f32x4 v1 = {p1.x, p1.y, p1.z, p1.w};
  __builtin_nontemporal_store(v0, pp + lane);
  __builtin_nontemporal_store(v1, pp + 64 + lane);
  if (lane == 0) {
    part_ms[W * 2 + 0] = m;
    part_ms[W * 2 + 1] = l;
  }
}

// ---------------------------------------------------------------------------
// Kernel 3: merge 96 wave-partials per batch into normalized pool[b,:].
// grid = B*4 (b, dg); block 512 = 128 d x 4 chunk-groups (24 chunks each).
// ---------------------------------------------------------------------------
__global__ __launch_bounds__(512) void k_merge(
    const float* __restrict__ part_pool, const float* __restrict__ part_ms,
    float* __restrict__ pool) {
  const int b   = blockIdx.x >> 2;
  const int dg  = blockIdx.x & 3;
  const int tid = threadIdx.x;
  const int lane = tid & 63;
  const int base = b * WPB;
  __shared__ float scl[WPB];
  __shared__ float red[4][128];

  // wave-parallel global (M, Z) over 96 partials (each wave redundantly)
  const float mA = part_ms[(base + lane) * 2 + 0];
  const float lA = part_ms[(base + lane) * 2 + 1];
  float mB = -INFINITY, lB = 0.0f;
  if (lane < WPB - 64) {
    mB = part_ms[(base + 64 + lane) * 2 + 0];
    lB = part_ms[(base + 64 + lane) * 2 + 1];
  }
  float M = fmaxf(mA, mB);
#pragma unroll
  for (int off = 32; off > 0; off >>= 1) M = fmaxf(M, __shfl_xor(M, off));
  float Z = __expf(mA - M) * lA + ((lane < WPB - 64) ? __expf(mB - M) * lB : 0.0f);
#pragma unroll
  for (int off = 32; off > 0; off >>= 1) Z += __shfl_xor(Z, off);
  const float invZ = 1.0f / Z;
  if (tid < WPB) scl[tid] = __expf(part_ms[(base + tid) * 2] - M);
  __syncthreads();

  const int dl = tid & 127;
  const int cg = tid >> 7;
  float acc = 0.0f;
#pragma unroll 8
  for (int i = 0; i < 24; ++i) {
    const int c = cg * 24 + i;
    acc += scl[c] * part_pool[((size_t)base + c) * DD + dg * 128 + dl];
  }
  red[cg][dl] = acc;
  __syncthreads();
  if (tid < 128)
    pool[b * DD + dg * 128 + tid] =
        (red[0][tid] + red[1][tid] + red[2][tid] + red[3][tid]) * invZ;
}

// ---------------------------------------------------------------------------
// Kernel 4: out = pool @ Wout + bout. grid = B*8 (b,jg); block 256 = 4kg x 64j.
// (bid&7 == jg -> each XCD sees one jg column-slab -> Wout L2-resident)
// ---------------------------------------------------------------------------
__global__ __launch_bounds__(256) void k_out(
    const float* __restrict__ pool, const float* __restrict__ Wout,
    const float* __restrict__ bout, float* __restrict__ out) {
  const int b   = blockIdx.x >> 3;
  const int jg  = blockIdx.x & 7;
  const int tid = threadIdx.x;
  const int kg  = tid >> 6;
  const int j   = tid & 63;
  const int jc  = jg * 64 + j;
  __shared__ float p[DD];
  __shared__ float red[4][64];

  p[tid] = pool[b * DD + tid];
  p[tid + 256] = pool[b * DD + 256 + tid];
  __syncthreads();

  float acc = 0.0f;
#pragma unroll 8
  for (int kk = 0; kk < 128; ++kk) {
    const int k = kg * 128 + kk;
    acc += p[k] * Wout[(size_t)k * DD + jc];
  }
  red[kg][j] = acc;
  __syncthreads();
  if (tid < 64) {
    const int jj = jg * 64 + tid;
    float o = red[0][tid] + red[1][tid] + red[2][tid] + red[3][tid] + bout[jj];
    if (jj < SS) out[b * SS + jj] = o;                       // mu
    else         out[BB * SS + b * SS + (jj - SS)] = o;      // log_sigma
  }
}

// ---------------------------------------------------------------------------
extern "C" void kernel_launch(void* const* d_in, const int* in_sizes, int n_in,
                              void* d_out, int out_size, void* d_ws, size_t ws_size,
                              hipStream_t stream) {
  const float* ctx    = (const float*)d_in[0];   // (B,T,D)
  const float* t_star = (const float*)d_in[1];   // (B,)
  const float* t_ctx  = (const float*)d_in[2];   // (B,T,1)
  const float* W1     = (const float*)d_in[3];   // (1,D)
  const float* b1     = (const float*)d_in[4];   // (D,)
  const float* W2     = (const float*)d_in[5];   // (D,D)
  const float* b2     = (const float*)d_in[6];   // (D,)
  const float* Wout   = (const float*)d_in[7];   // (D,2S)
  const float* bout   = (const float*)d_in[8];   // (2S,)
  float* out = (float*)d_out;

  float* ws = (float*)d_ws;
  float* q         = ws;                                   // B*D
  float* part_pool = q + (size_t)BB * DD;                  // B*WPB*D (6.3 MB)
  float* part_ms   = part_pool + (size_t)BB * WPB * DD;    // B*WPB*2
  float* pool      = part_ms + (size_t)BB * WPB * 2;       // B*D

  k_q<<<BB * 8, 512, 0, stream>>>(t_star, W1, b1, W2, b2, q);
  k_fused<<<NBLK, 256, 0, stream>>>(ctx, q, t_star, t_ctx, part_pool, part_ms);
  k_merge<<<BB * 4, 512, 0, stream>>>(part_pool, part_ms, pool);
  k_out<<<BB * 8, 256, 0, stream>>>(pool, Wout, bout, out);
}